// Round 3
// baseline (176.191 us; speedup 1.0000x reference)
//
#include <hip/hip_runtime.h>
#include <stdint.h>

#define N_NODES 100000
#define KNBR 16
#define ALPHA 0.2f

typedef __attribute__((ext_vector_type(8))) short bf16x8;
typedef __attribute__((ext_vector_type(4))) float f32x4;
typedef unsigned short u16;
typedef unsigned int u32;

static __device__ __forceinline__ u16 f2bf(float f) {
  u32 u = __builtin_bit_cast(u32, f);
  u += 0x7fffu + ((u >> 16) & 1u);   // round-to-nearest-even
  return (u16)(u >> 16);
}
static __device__ __forceinline__ float bf2f(u16 s) {
  return __builtin_bit_cast(float, ((u32)s) << 16);
}

// ---- Kernel 1: W -> Wb in MFMA B-fragment order ----
// frag(ks, ct): lane l, elem i = W[ks*32 + (l>>4)*8 + i][ct*16 + (l&15)]
__global__ __launch_bounds__(256) void prep_w_kernel(const float* __restrict__ W,
                                                     u16* __restrict__ Wb) {
  const int t = blockIdx.x * 256 + threadIdx.x;  // 0..8191
  const int l = t & 63;
  const int ct = (t >> 6) & 15;
  const int ks = t >> 10;
  const int colbase = ct * 16 + (l & 15);
  const int k0 = ks * 32 + (l >> 4) * 8;
  u32 wq[4];
#pragma unroll
  for (int q = 0; q < 4; ++q) {
    const u16 b0 = f2bf(W[(k0 + 2 * q) * 256 + colbase]);
    const u16 b1 = f2bf(W[(k0 + 2 * q + 1) * 256 + colbase]);
    wq[q] = (u32)b0 | ((u32)b1 << 16);
  }
  uint4 o = {wq[0], wq[1], wq[2], wq[3]};
  *(uint4*)(Wb + (size_t)t * 8) = o;
}

// ---- Kernel 2: dense GEMM  Y = bf16(h @ W), 32 rows per block ----
__global__ __launch_bounds__(256, 4) void gemm_kernel(const float* __restrict__ h,
                                                      const u16* __restrict__ Wb,
                                                      u16* __restrict__ Y) {
  __shared__ __align__(16) u16 aS[32 * 256];   // 16 KB, XOR-swizzled rows
  const int tid = threadIdx.x;
  const int blk = blockIdx.x;
  const size_t base = (size_t)blk * (32 * 256);

  // stage 32x256 fp32 -> bf16 LDS (swizzled for conflict-free ds_read_b128)
#pragma unroll
  for (int i = 0; i < 8; ++i) {
    const int flat = i * 1024 + tid * 4;       // float index in tile
    const int row = flat >> 8, d0 = flat & 255;
    const float4 v = *(const float4*)(h + base + flat);
    uint2 o;
    o.x = (u32)f2bf(v.x) | ((u32)f2bf(v.y) << 16);
    o.y = (u32)f2bf(v.z) | ((u32)f2bf(v.w) << 16);
    *(uint2*)((char*)aS + row * 512 + ((d0 * 2) ^ ((row & 7) << 4))) = o;
  }
  __syncthreads();

  // MFMA: A = aS[32x256], B = Wb fragments (L2-resident)
  const int l = tid & 63, wv = tid >> 6;
  const int l15 = l & 15, lg = l >> 4;
  f32x4 acc[2][4] = {};
  const uint4* wbL = ((const uint4*)Wb) + (size_t)(wv * 4) * 64 + l;
  const char* aggB = (const char*)aS;
  const int rb0 = l15 * 512;
  const int xm = (l15 & 7) << 4;
#pragma unroll 2
  for (int ks = 0; ks < 8; ++ks) {
    const int offk = ((ks * 64) + lg * 16) ^ xm;
    const bf16x8 a0 = *(const bf16x8*)(aggB + rb0 + offk);
    const bf16x8 a1 = *(const bf16x8*)(aggB + rb0 + 8192 + offk);
#pragma unroll
    for (int c = 0; c < 4; ++c) {
      const uint4 bw = wbL[ks * 1024 + c * 64];
      const bf16x8 b = __builtin_bit_cast(bf16x8, bw);
      acc[0][c] = __builtin_amdgcn_mfma_f32_16x16x32_bf16(a0, b, acc[0][c], 0, 0, 0);
      acc[1][c] = __builtin_amdgcn_mfma_f32_16x16x32_bf16(a1, b, acc[1][c], 0, 0, 0);
    }
  }

  // store Y bf16 (scalar u16 stores; L2 write-combines adjacent 32B runs)
  u16* yp = Y + base + wv * 64;
#pragma unroll
  for (int rt = 0; rt < 2; ++rt)
#pragma unroll
    for (int j = 0; j < 4; ++j) {
      const int r = rt * 16 + lg * 4 + j;
#pragma unroll
      for (int c = 0; c < 4; ++c)
        yp[r * 256 + c * 16 + l15] = f2bf(acc[rt][c][j]);
    }
}

// ---- Kernel 3: gather-mean in Y-space + leaky + L2-normalize ----
// One wave per node; 17 x 8B loads per lane, all in flight; indices in SGPRs.
__global__ __launch_bounds__(256, 8) void gather_kernel(const u16* __restrict__ Y,
                                                        const int* __restrict__ nbr,
                                                        float* __restrict__ out) {
  const int tid = threadIdx.x;
  const int lane = tid & 63, wv = tid >> 6;
  const int node = blockIdx.x * 4 + wv;

  const int il = nbr[node * KNBR + (lane & 15)];  // lanes 16..63 replicate
  const uint2* yb = (const uint2*)Y;              // 8B units: row*64 + lane

  uint2 v[17];
  v[0] = yb[(size_t)node * 64 + lane];
#pragma unroll
  for (int j = 0; j < 16; ++j) {
    const int r = __builtin_amdgcn_readlane(il, j);   // wave-uniform -> SGPR
    v[j + 1] = yb[(size_t)r * 64 + lane];
  }

  float a0 = 0.f, a1 = 0.f, a2 = 0.f, a3 = 0.f;
#pragma unroll
  for (int j = 0; j < 17; ++j) {
    a0 += bf2f((u16)(v[j].x & 0xffff));
    a1 += bf2f((u16)(v[j].x >> 16));
    a2 += bf2f((u16)(v[j].y & 0xffff));
    a3 += bf2f((u16)(v[j].y >> 16));
  }
  const float s = 1.0f / 17.0f;
  a0 *= s; a1 *= s; a2 *= s; a3 *= s;
  a0 = (a0 >= 0.f) ? a0 : ALPHA * a0;
  a1 = (a1 >= 0.f) ? a1 : ALPHA * a1;
  a2 = (a2 >= 0.f) ? a2 : ALPHA * a2;
  a3 = (a3 >= 0.f) ? a3 : ALPHA * a3;

  float ss = a0 * a0 + a1 * a1 + a2 * a2 + a3 * a3;
  ss += __shfl_xor(ss, 1);  ss += __shfl_xor(ss, 2);
  ss += __shfl_xor(ss, 4);  ss += __shfl_xor(ss, 8);
  ss += __shfl_xor(ss, 16); ss += __shfl_xor(ss, 32);
  const float inv = 1.0f / fmaxf(sqrtf(ss), 1e-12f);

  f32x4 o = {a0 * inv, a1 * inv, a2 * inv, a3 * inv};
  __builtin_nontemporal_store(o, (f32x4*)(out + (size_t)node * 256 + lane * 4));
}

extern "C" void kernel_launch(void* const* d_in, const int* in_sizes, int n_in,
                              void* d_out, int out_size, void* d_ws, size_t ws_size,
                              hipStream_t stream) {
  const float* h = (const float*)d_in[0];
  const int* nbr = (const int*)d_in[1];
  const float* W = (const float*)d_in[2];
  float* out = (float*)d_out;

  u16* Wb = (u16*)d_ws;                    // 128 KB fragment-ordered W
  u16* Y = (u16*)((char*)d_ws + 131072);   // 51.2 MB bf16 Y = h @ W

  prep_w_kernel<<<32, 256, 0, stream>>>(W, Wb);
  gemm_kernel<<<N_NODES / 32, 256, 0, stream>>>(h, Wb, Y);
  gather_kernel<<<N_NODES / 4, 256, 0, stream>>>(Y, nbr, out);
}

// Round 4
// 175.905 us; speedup vs baseline: 1.0016x; 1.0016x over previous
//
#include <hip/hip_runtime.h>
#include <stdint.h>

#define N_NODES 100000
#define KNBR 16
#define ALPHA 0.2f

typedef __attribute__((ext_vector_type(8))) short bf16x8;
typedef __attribute__((ext_vector_type(4))) float f32x4;
typedef unsigned short u16;
typedef unsigned int u32;

static __device__ __forceinline__ u16 f2bf(float f) {
  u32 u = __builtin_bit_cast(u32, f);
  u += 0x7fffu + ((u >> 16) & 1u);   // round-to-nearest-even
  return (u16)(u >> 16);
}
static __device__ __forceinline__ float bf2f(u16 s) {
  return __builtin_bit_cast(float, ((u32)s) << 16);
}

// ---- Kernel 1: W -> Wb in MFMA B-fragment order ----
// frag(ks, ct): lane l, elem i = W[ks*32 + (l>>4)*8 + i][ct*16 + (l&15)]
__global__ __launch_bounds__(256) void prep_w_kernel(const float* __restrict__ W,
                                                     u16* __restrict__ Wb) {
  const int t = blockIdx.x * 256 + threadIdx.x;  // 0..8191
  const int l = t & 63;
  const int ct = (t >> 6) & 15;
  const int ks = t >> 10;
  const int colbase = ct * 16 + (l & 15);
  const int k0 = ks * 32 + (l >> 4) * 8;
  u32 wq[4];
#pragma unroll
  for (int q = 0; q < 4; ++q) {
    const u16 b0 = f2bf(W[(k0 + 2 * q) * 256 + colbase]);
    const u16 b1 = f2bf(W[(k0 + 2 * q + 1) * 256 + colbase]);
    wq[q] = (u32)b0 | ((u32)b1 << 16);
  }
  uint4 o = {wq[0], wq[1], wq[2], wq[3]};
  *(uint4*)(Wb + (size_t)t * 8) = o;
}

// ---- Kernel 2: dense GEMM  Y = bf16(h @ W), 32 rows per block ----
__global__ __launch_bounds__(256, 4) void gemm_kernel(const float* __restrict__ h,
                                                      const u16* __restrict__ Wb,
                                                      u16* __restrict__ Y) {
  __shared__ __align__(16) u16 aS[32 * 256];   // 16 KB, XOR-swizzled rows
  const int tid = threadIdx.x;
  const int blk = blockIdx.x;
  const size_t base = (size_t)blk * (32 * 256);

  // stage 32x256 fp32 -> bf16 LDS (swizzled for conflict-free ds_read_b128)
#pragma unroll
  for (int i = 0; i < 8; ++i) {
    const int flat = i * 1024 + tid * 4;       // float index in tile
    const int row = flat >> 8, d0 = flat & 255;
    const float4 v = *(const float4*)(h + base + flat);
    uint2 o;
    o.x = (u32)f2bf(v.x) | ((u32)f2bf(v.y) << 16);
    o.y = (u32)f2bf(v.z) | ((u32)f2bf(v.w) << 16);
    *(uint2*)((char*)aS + row * 512 + ((d0 * 2) ^ ((row & 7) << 4))) = o;
  }
  __syncthreads();

  // MFMA: A = aS[32x256], B = Wb fragments (L2-resident)
  const int l = tid & 63, wv = tid >> 6;
  const int l15 = l & 15, lg = l >> 4;
  f32x4 acc[2][4] = {};
  const uint4* wbL = ((const uint4*)Wb) + (size_t)(wv * 4) * 64 + l;
  const char* aggB = (const char*)aS;
  const int rb0 = l15 * 512;
  const int xm = (l15 & 7) << 4;
#pragma unroll 2
  for (int ks = 0; ks < 8; ++ks) {
    const int offk = ((ks * 64) + lg * 16) ^ xm;
    const bf16x8 a0 = *(const bf16x8*)(aggB + rb0 + offk);
    const bf16x8 a1 = *(const bf16x8*)(aggB + rb0 + 8192 + offk);
#pragma unroll
    for (int c = 0; c < 4; ++c) {
      const uint4 bw = wbL[ks * 1024 + c * 64];
      const bf16x8 b = __builtin_bit_cast(bf16x8, bw);
      acc[0][c] = __builtin_amdgcn_mfma_f32_16x16x32_bf16(a0, b, acc[0][c], 0, 0, 0);
      acc[1][c] = __builtin_amdgcn_mfma_f32_16x16x32_bf16(a1, b, acc[1][c], 0, 0, 0);
    }
  }

  // Epilogue: bounce through LDS (lg-XOR on 32B chunks keeps banks spread),
  // then fully-coalesced 16B stores: wave writes 1KB contiguous runs.
  __syncthreads();   // all aS reads done; safe to overwrite
#pragma unroll
  for (int rt = 0; rt < 2; ++rt)
#pragma unroll
    for (int j = 0; j < 4; ++j) {
      const int r = rt * 16 + lg * 4 + j;
#pragma unroll
      for (int c = 0; c < 4; ++c)
        aS[r * 256 + ((wv * 64 + c * 16 + l15) ^ (lg * 16))] = f2bf(acc[rt][c][j]);
    }
  __syncthreads();
  const uint4* as4 = (const uint4*)aS;
  uint4* y4 = (uint4*)(Y + base);
#pragma unroll
  for (int q = 0; q < 4; ++q) {
    const int flat = q * 256 + tid;            // uint4 index in tile
    const int row = flat >> 5;                 // 32 u16 per row-chunk of 8
    const int col8 = (flat & 31) * 8;          // first u16 col of this 16B
    const int colx = col8 ^ (((row >> 2) & 3) * 16);
    y4[q * 256 + tid] = as4[(row * 256 + colx) >> 3];
  }
}

// ---- Kernel 3: gather-mean in Y-space + leaky + L2-normalize ----
// One wave per node; 17 x 8B loads ALL in flight (sched_barrier pins issue
// order ahead of uses -> deep MLP); indices in SGPRs via readlane.
__global__ __launch_bounds__(256, 6) void gather_kernel(const u16* __restrict__ Y,
                                                        const int* __restrict__ nbr,
                                                        float* __restrict__ out) {
  const int tid = threadIdx.x;
  const int lane = tid & 63, wv = tid >> 6;
  const int node = blockIdx.x * 4 + wv;

  const int il = nbr[node * KNBR + (lane & 15)];  // lanes 16..63 replicate
  const uint2* yb = (const uint2*)Y;              // 8B units: row*64 + lane

  uint2 v[17];
  v[0] = yb[(size_t)node * 64 + lane];
#pragma unroll
  for (int j = 0; j < 16; ++j) {
    const int r = __builtin_amdgcn_readlane(il, j);   // wave-uniform -> SGPR
    v[j + 1] = yb[(size_t)r * 64 + lane];
  }
  __builtin_amdgcn_sched_barrier(0);   // keep all 17 loads in flight

  float a0 = 0.f, a1 = 0.f, a2 = 0.f, a3 = 0.f;
#pragma unroll
  for (int j = 0; j < 17; ++j) {
    a0 += bf2f((u16)(v[j].x & 0xffff));
    a1 += bf2f((u16)(v[j].x >> 16));
    a2 += bf2f((u16)(v[j].y & 0xffff));
    a3 += bf2f((u16)(v[j].y >> 16));
  }
  const float s = 1.0f / 17.0f;
  a0 *= s; a1 *= s; a2 *= s; a3 *= s;
  a0 = (a0 >= 0.f) ? a0 : ALPHA * a0;
  a1 = (a1 >= 0.f) ? a1 : ALPHA * a1;
  a2 = (a2 >= 0.f) ? a2 : ALPHA * a2;
  a3 = (a3 >= 0.f) ? a3 : ALPHA * a3;

  float ss = a0 * a0 + a1 * a1 + a2 * a2 + a3 * a3;
  ss += __shfl_xor(ss, 1);  ss += __shfl_xor(ss, 2);
  ss += __shfl_xor(ss, 4);  ss += __shfl_xor(ss, 8);
  ss += __shfl_xor(ss, 16); ss += __shfl_xor(ss, 32);
  const float inv = 1.0f / fmaxf(sqrtf(ss), 1e-12f);

  f32x4 o = {a0 * inv, a1 * inv, a2 * inv, a3 * inv};
  __builtin_nontemporal_store(o, (f32x4*)(out + (size_t)node * 256 + lane * 4));
}

extern "C" void kernel_launch(void* const* d_in, const int* in_sizes, int n_in,
                              void* d_out, int out_size, void* d_ws, size_t ws_size,
                              hipStream_t stream) {
  const float* h = (const float*)d_in[0];
  const int* nbr = (const int*)d_in[1];
  const float* W = (const float*)d_in[2];
  float* out = (float*)d_out;

  u16* Wb = (u16*)d_ws;                    // 128 KB fragment-ordered W
  u16* Y = (u16*)((char*)d_ws + 131072);   // 51.2 MB bf16 Y = h @ W

  prep_w_kernel<<<32, 256, 0, stream>>>(W, Wb);
  gemm_kernel<<<N_NODES / 32, 256, 0, stream>>>(h, Wb, Y);
  gather_kernel<<<N_NODES / 4, 256, 0, stream>>>(Y, nbr, out);
}

// Round 5
// 114.392 us; speedup vs baseline: 1.5402x; 1.5377x over previous
//
#include <hip/hip_runtime.h>
#include <stdint.h>

#define N_NODES 100000
#define KNBR 16
#define ALPHA 0.2f

typedef __attribute__((ext_vector_type(8))) short bf16x8;
typedef __attribute__((ext_vector_type(4))) float f32x4;
typedef __attribute__((ext_vector_type(4))) unsigned int u32x4;
typedef unsigned short u16;
typedef unsigned int u32;
typedef unsigned char u8;

static __device__ __forceinline__ u16 f2bf(float f) {
  u32 u = __builtin_bit_cast(u32, f);
  u += 0x7fffu + ((u >> 16) & 1u);   // round-to-nearest-even
  return (u16)(u >> 16);
}

static __device__ __forceinline__ float ubyte(u32 v, int k) {
  return (float)((v >> (8 * k)) & 0xffu);   // ISel -> v_cvt_f32_ubyteN
}

// ---- Kernel 1: W -> Wb in MFMA B-fragment order ----
// frag(ks, ct): lane l, elem i = W[ks*32 + (l>>4)*8 + i][ct*16 + (l&15)]
__global__ __launch_bounds__(256) void prep_w_kernel(const float* __restrict__ W,
                                                     u16* __restrict__ Wb) {
  const int t = blockIdx.x * 256 + threadIdx.x;  // 0..8191
  const int l = t & 63;
  const int ct = (t >> 6) & 15;
  const int ks = t >> 10;
  const int colbase = ct * 16 + (l & 15);
  const int k0 = ks * 32 + (l >> 4) * 8;
  u32 wq[4];
#pragma unroll
  for (int q = 0; q < 4; ++q) {
    const u16 b0 = f2bf(W[(k0 + 2 * q) * 256 + colbase]);
    const u16 b1 = f2bf(W[(k0 + 2 * q + 1) * 256 + colbase]);
    wq[q] = (u32)b0 | ((u32)b1 << 16);
  }
  uint4 o = {wq[0], wq[1], wq[2], wq[3]};
  *(uint4*)(Wb + (size_t)t * 8) = o;
}

// ---- Kernel 2: GEMM Y = h @ W, then per-row int8 quantization ----
// Yq[node][256] biased uint8, scale[node] = rowmax/127 (f32).
__global__ __launch_bounds__(256, 4) void gemm_kernel(const float* __restrict__ h,
                                                      const u16* __restrict__ Wb,
                                                      u8* __restrict__ Yq,
                                                      float* __restrict__ scale) {
  __shared__ __align__(16) u16 aS[32 * 256];   // 16 KB: bf16 A-tile, then u8 quant tile
  __shared__ float redS[4][32];
  __shared__ float invSS[32];
  const int tid = threadIdx.x;
  const int blk = blockIdx.x;
  const size_t base = (size_t)blk * (32 * 256);

  // stage 32x256 fp32 -> bf16 LDS (swizzled for conflict-free ds_read_b128)
#pragma unroll
  for (int i = 0; i < 8; ++i) {
    const int flat = i * 1024 + tid * 4;       // float index in tile
    const int row = flat >> 8, d0 = flat & 255;
    const float4 v = *(const float4*)(h + base + flat);
    uint2 o;
    o.x = (u32)f2bf(v.x) | ((u32)f2bf(v.y) << 16);
    o.y = (u32)f2bf(v.z) | ((u32)f2bf(v.w) << 16);
    *(uint2*)((char*)aS + row * 512 + ((d0 * 2) ^ ((row & 7) << 4))) = o;
  }
  __syncthreads();

  // MFMA: A = aS[32x256], B = Wb fragments (L2-resident)
  const int l = tid & 63, wv = tid >> 6;
  const int l15 = l & 15, lg = l >> 4;
  f32x4 acc[2][4] = {};
  const uint4* wbL = ((const uint4*)Wb) + (size_t)(wv * 4) * 64 + l;
  const char* aggB = (const char*)aS;
  const int rb0 = l15 * 512;
  const int xm = (l15 & 7) << 4;
#pragma unroll 2
  for (int ks = 0; ks < 8; ++ks) {
    const int offk = ((ks * 64) + lg * 16) ^ xm;
    const bf16x8 a0 = *(const bf16x8*)(aggB + rb0 + offk);
    const bf16x8 a1 = *(const bf16x8*)(aggB + rb0 + 8192 + offk);
#pragma unroll
    for (int c = 0; c < 4; ++c) {
      const uint4 bw = wbL[ks * 1024 + c * 64];
      const bf16x8 b = __builtin_bit_cast(bf16x8, bw);
      acc[0][c] = __builtin_amdgcn_mfma_f32_16x16x32_bf16(a0, b, acc[0][c], 0, 0, 0);
      acc[1][c] = __builtin_amdgcn_mfma_f32_16x16x32_bf16(a1, b, acc[1][c], 0, 0, 0);
    }
  }

  // ---- rowmax over 256 cols (shfl within 16-lane group + LDS across waves) ----
#pragma unroll
  for (int rt = 0; rt < 2; ++rt)
#pragma unroll
    for (int j = 0; j < 4; ++j) {
      float m = 0.f;
#pragma unroll
      for (int c = 0; c < 4; ++c) m = fmaxf(m, fabsf(acc[rt][c][j]));
      m = fmaxf(m, __shfl_xor(m, 1)); m = fmaxf(m, __shfl_xor(m, 2));
      m = fmaxf(m, __shfl_xor(m, 4)); m = fmaxf(m, __shfl_xor(m, 8));
      redS[wv][rt * 16 + lg * 4 + j] = m;   // same value from 16 lanes: benign
    }
  __syncthreads();
  if (tid < 32) {
    float m = fmaxf(fmaxf(redS[0][tid], redS[1][tid]),
                    fmaxf(redS[2][tid], redS[3][tid]));
    m = fmaxf(m, 1e-20f);
    scale[blk * 32 + tid] = m * (1.0f / 127.0f);
    invSS[tid] = 127.0f / m;
  }
  __syncthreads();

  // ---- quantize into LDS u8 tile (XOR-swizzled: conflict-free across lg) ----
  u8* qS = (u8*)aS;
#pragma unroll
  for (int rt = 0; rt < 2; ++rt)
#pragma unroll
    for (int j = 0; j < 4; ++j) {
      const int r = rt * 16 + lg * 4 + j;
      const float inv = invSS[r];
      const int sw = ((r >> 2) & 7) << 5;
#pragma unroll
      for (int c = 0; c < 4; ++c) {
        float q = rintf(acc[rt][c][j] * inv);
        q = fminf(127.f, fmaxf(-127.f, q));
        qS[r * 256 + ((wv * 64 + c * 16 + l15) ^ sw)] = (u8)((int)q + 128);
      }
    }
  __syncthreads();

  // ---- coalesced 16B stores of the quant tile ----
  const u32x4* q4 = (const u32x4*)aS;
  u32x4* yg = (u32x4*)(Yq + (size_t)blk * 8192);
#pragma unroll
  for (int q = 0; q < 2; ++q) {
    const int f = q * 4096 + tid * 16;         // byte index in tile
    const int row = f >> 8, col = f & 255;
    const int colx = col ^ (((row >> 2) & 7) << 5);
    __builtin_nontemporal_store(q4[(row * 256 + colx) >> 4], &yg[f >> 4]);
  }
}

// ---- Kernel 3: gather-mean (int8 Y-space) + leaky + L2-normalize ----
__global__ __launch_bounds__(256) void gather_kernel(const u8* __restrict__ Yq,
                                                     const float* __restrict__ scale,
                                                     const int* __restrict__ nbr,
                                                     float* __restrict__ out) {
  const int tid = threadIdx.x;
  const int lane = tid & 63, wv = tid >> 6;
  const int node = __builtin_amdgcn_readfirstlane(blockIdx.x * 4 + wv);

  const int il = nbr[node * KNBR + (lane & 15)];  // lanes 16..63 replicate
  const float vscale = scale[il];                 // per-lane 4B gather (L2-hot)
  const float sself = scale[node];                // wave-uniform -> s_load
  const u32* yb = (const u32*)Yq;                 // 4B units: row*64 + lane

  u32 v[17];
  v[0] = yb[(size_t)node * 64 + lane];
#pragma unroll
  for (int j = 0; j < 16; ++j) {
    const int r = __builtin_amdgcn_readlane(il, j);   // wave-uniform -> SGPR
    v[j + 1] = yb[(size_t)r * 64 + lane];
  }

  float a0, a1, a2, a3, S;
  S = sself;
  a0 = sself * ubyte(v[0], 0);
  a1 = sself * ubyte(v[0], 1);
  a2 = sself * ubyte(v[0], 2);
  a3 = sself * ubyte(v[0], 3);
#pragma unroll
  for (int j = 0; j < 16; ++j) {
    const float s = __builtin_bit_cast(
        float, __builtin_amdgcn_readlane(__builtin_bit_cast(int, vscale), j));
    S += s;
    a0 = fmaf(s, ubyte(v[j + 1], 0), a0);
    a1 = fmaf(s, ubyte(v[j + 1], 1), a1);
    a2 = fmaf(s, ubyte(v[j + 1], 2), a2);
    a3 = fmaf(s, ubyte(v[j + 1], 3), a3);
  }
  const float sc = 1.0f / 17.0f, bias = 128.0f * S;
  a0 = (a0 - bias) * sc; a1 = (a1 - bias) * sc;
  a2 = (a2 - bias) * sc; a3 = (a3 - bias) * sc;
  a0 = (a0 >= 0.f) ? a0 : ALPHA * a0;
  a1 = (a1 >= 0.f) ? a1 : ALPHA * a1;
  a2 = (a2 >= 0.f) ? a2 : ALPHA * a2;
  a3 = (a3 >= 0.f) ? a3 : ALPHA * a3;

  float ss = a0 * a0 + a1 * a1 + a2 * a2 + a3 * a3;
  ss += __shfl_xor(ss, 1);  ss += __shfl_xor(ss, 2);
  ss += __shfl_xor(ss, 4);  ss += __shfl_xor(ss, 8);
  ss += __shfl_xor(ss, 16); ss += __shfl_xor(ss, 32);
  const float inv = 1.0f / fmaxf(sqrtf(ss), 1e-12f);

  f32x4 o = {a0 * inv, a1 * inv, a2 * inv, a3 * inv};
  __builtin_nontemporal_store(o, (f32x4*)(out + (size_t)node * 256 + lane * 4));
}

extern "C" void kernel_launch(void* const* d_in, const int* in_sizes, int n_in,
                              void* d_out, int out_size, void* d_ws, size_t ws_size,
                              hipStream_t stream) {
  const float* h = (const float*)d_in[0];
  const int* nbr = (const int*)d_in[1];
  const float* W = (const float*)d_in[2];
  float* out = (float*)d_out;

  u16* Wb = (u16*)d_ws;                                  // 128 KB
  float* scale = (float*)((char*)d_ws + (1 << 17));      // 400 KB f32 row scales
  u8* Yq = (u8*)((char*)d_ws + (1 << 20));               // 25.6 MB int8 Y

  prep_w_kernel<<<32, 256, 0, stream>>>(W, Wb);
  gemm_kernel<<<N_NODES / 32, 256, 0, stream>>>(h, Wb, Yq, scale);
  gather_kernel<<<N_NODES / 4, 256, 0, stream>>>(Yq, scale, nbr, out);
}

// Round 6
// 113.424 us; speedup vs baseline: 1.5534x; 1.0085x over previous
//
#include <hip/hip_runtime.h>
#include <stdint.h>

#define N_NODES 100000
#define KNBR 16
#define ALPHA 0.2f

typedef __attribute__((ext_vector_type(8))) short bf16x8;
typedef __attribute__((ext_vector_type(4))) float f32x4;
typedef __attribute__((ext_vector_type(4))) unsigned int u32x4;
typedef unsigned short u16;
typedef unsigned int u32;
typedef unsigned char u8;

static __device__ __forceinline__ u16 f2bf(float f) {
  u32 u = __builtin_bit_cast(u32, f);
  u += 0x7fffu + ((u >> 16) & 1u);   // round-to-nearest-even
  return (u16)(u >> 16);
}

// ---- Kernel 1: W -> Wb in MFMA B-fragment order ----
// frag(ks, ct): lane l, elem i = W[ks*32 + (l>>4)*8 + i][ct*16 + (l&15)]
__global__ __launch_bounds__(256) void prep_w_kernel(const float* __restrict__ W,
                                                     u16* __restrict__ Wb) {
  const int t = blockIdx.x * 256 + threadIdx.x;  // 0..8191
  const int l = t & 63;
  const int ct = (t >> 6) & 15;
  const int ks = t >> 10;
  const int colbase = ct * 16 + (l & 15);
  const int k0 = ks * 32 + (l >> 4) * 8;
  u32 wq[4];
#pragma unroll
  for (int q = 0; q < 4; ++q) {
    const u16 b0 = f2bf(W[(k0 + 2 * q) * 256 + colbase]);
    const u16 b1 = f2bf(W[(k0 + 2 * q + 1) * 256 + colbase]);
    wq[q] = (u32)b0 | ((u32)b1 << 16);
  }
  uint4 o = {wq[0], wq[1], wq[2], wq[3]};
  *(uint4*)(Wb + (size_t)t * 8) = o;
}

// ---- Kernel 2: GEMM Y = h @ W, then per-row int8 quantization ----
// Yq[node][256] biased uint8, scale[node] = rowmax/127 (f32).
__global__ __launch_bounds__(256, 4) void gemm_kernel(const float* __restrict__ h,
                                                      const u16* __restrict__ Wb,
                                                      u8* __restrict__ Yq,
                                                      float* __restrict__ scale) {
  __shared__ __align__(16) u16 aS[32 * 256];   // 16 KB: bf16 A-tile, then u8 quant tile
  __shared__ float redS[4][32];
  __shared__ float invSS[32];
  const int tid = threadIdx.x;
  const int blk = blockIdx.x;
  const size_t base = (size_t)blk * (32 * 256);

  // stage 32x256 fp32 -> bf16 LDS (NT loads: h is streamed exactly once)
#pragma unroll
  for (int i = 0; i < 8; ++i) {
    const int flat = i * 1024 + tid * 4;       // float index in tile
    const int row = flat >> 8, d0 = flat & 255;
    const f32x4 v = __builtin_nontemporal_load((const f32x4*)(h + base + flat));
    uint2 o;
    o.x = (u32)f2bf(v[0]) | ((u32)f2bf(v[1]) << 16);
    o.y = (u32)f2bf(v[2]) | ((u32)f2bf(v[3]) << 16);
    *(uint2*)((char*)aS + row * 512 + ((d0 * 2) ^ ((row & 7) << 4))) = o;
  }
  __syncthreads();

  // MFMA: A = aS[32x256], B = Wb fragments (L2-resident)
  const int l = tid & 63, wv = tid >> 6;
  const int l15 = l & 15, lg = l >> 4;
  f32x4 acc[2][4] = {};
  const uint4* wbL = ((const uint4*)Wb) + (size_t)(wv * 4) * 64 + l;
  const char* aggB = (const char*)aS;
  const int rb0 = l15 * 512;
  const int xm = (l15 & 7) << 4;
#pragma unroll 2
  for (int ks = 0; ks < 8; ++ks) {
    const int offk = ((ks * 64) + lg * 16) ^ xm;
    const bf16x8 a0 = *(const bf16x8*)(aggB + rb0 + offk);
    const bf16x8 a1 = *(const bf16x8*)(aggB + rb0 + 8192 + offk);
#pragma unroll
    for (int c = 0; c < 4; ++c) {
      const uint4 bw = wbL[ks * 1024 + c * 64];
      const bf16x8 b = __builtin_bit_cast(bf16x8, bw);
      acc[0][c] = __builtin_amdgcn_mfma_f32_16x16x32_bf16(a0, b, acc[0][c], 0, 0, 0);
      acc[1][c] = __builtin_amdgcn_mfma_f32_16x16x32_bf16(a1, b, acc[1][c], 0, 0, 0);
    }
  }

  // ---- rowmax over 256 cols (shfl within 16-lane group + LDS across waves) ----
#pragma unroll
  for (int rt = 0; rt < 2; ++rt)
#pragma unroll
    for (int j = 0; j < 4; ++j) {
      float m = 0.f;
#pragma unroll
      for (int c = 0; c < 4; ++c) m = fmaxf(m, fabsf(acc[rt][c][j]));
      m = fmaxf(m, __shfl_xor(m, 1)); m = fmaxf(m, __shfl_xor(m, 2));
      m = fmaxf(m, __shfl_xor(m, 4)); m = fmaxf(m, __shfl_xor(m, 8));
      redS[wv][rt * 16 + lg * 4 + j] = m;   // same value from 16 lanes: benign
    }
  __syncthreads();
  if (tid < 32) {
    float m = fmaxf(fmaxf(redS[0][tid], redS[1][tid]),
                    fmaxf(redS[2][tid], redS[3][tid]));
    m = fmaxf(m, 1e-20f);
    scale[blk * 32 + tid] = m * (1.0f / 127.0f);
    invSS[tid] = 127.0f / m;
  }
  __syncthreads();

  // ---- quantize into LDS u8 tile (XOR-swizzled: conflict-free across lg) ----
  u8* qS = (u8*)aS;
#pragma unroll
  for (int rt = 0; rt < 2; ++rt)
#pragma unroll
    for (int j = 0; j < 4; ++j) {
      const int r = rt * 16 + lg * 4 + j;
      const float inv = invSS[r];
      const int sw = ((r >> 2) & 7) << 5;
#pragma unroll
      for (int c = 0; c < 4; ++c) {
        float q = rintf(acc[rt][c][j] * inv);
        q = fminf(127.f, fmaxf(-127.f, q));
        qS[r * 256 + ((wv * 64 + c * 16 + l15) ^ sw)] = (u8)((int)q + 128);
      }
    }
  __syncthreads();

  // ---- coalesced 16B stores of the quant tile ----
  const u32x4* q4 = (const u32x4*)aS;
  u32x4* yg = (u32x4*)(Yq + (size_t)blk * 8192);
#pragma unroll
  for (int q = 0; q < 2; ++q) {
    const int f = q * 4096 + tid * 16;         // byte index in tile
    const int row = f >> 8, col = f & 255;
    const int colx = col ^ (((row >> 2) & 7) << 5);
    __builtin_nontemporal_store(q4[(row * 256 + colx) >> 4], &yg[f >> 4]);
  }
}

// ---- Kernel 3: gather-mean (int8 Y-space) + leaky + L2-normalize ----
// All per-node index/scale/address work on the SCALAR pipe (wave-uniform
// s_loads); VALU does only cvt_f32_ubyte + fma. 17 saddr loads in flight.
__global__ __launch_bounds__(256) void gather_kernel(const u8* __restrict__ Yq,
                                                     const float* __restrict__ scale,
                                                     const int* __restrict__ nbr,
                                                     float* __restrict__ out) {
  const int tid = threadIdx.x;
  const int lane = tid & 63, wv = tid >> 6;
  const int node = __builtin_amdgcn_readfirstlane(blockIdx.x * 4 + wv);

  // wave-uniform indices -> SMEM s_load (nbr row is 64B contiguous)
  int idx[17];
  idx[0] = node;
#pragma unroll
  for (int j = 0; j < 16; ++j) idx[j + 1] = nbr[node * KNBR + j];

  // wave-uniform scales -> scattered s_load_dword (L2-hot, 400KB array)
  float s[17];
#pragma unroll
  for (int j = 0; j < 17; ++j) s[j] = scale[idx[j]];

  // 17 row loads, saddr form: uniform base + shared lane*4 voffset
  u32 v[17];
#pragma unroll
  for (int j = 0; j < 17; ++j)
    v[j] = *(const u32*)(Yq + (size_t)idx[j] * 256 + lane * 4);

  float a0 = 0.f, a1 = 0.f, a2 = 0.f, a3 = 0.f, S = 0.f;
#pragma unroll
  for (int j = 0; j < 17; ++j) {
    float f0, f1, f2, f3;
    asm("v_cvt_f32_ubyte0 %0, %1" : "=v"(f0) : "v"(v[j]));
    asm("v_cvt_f32_ubyte1 %0, %1" : "=v"(f1) : "v"(v[j]));
    asm("v_cvt_f32_ubyte2 %0, %1" : "=v"(f2) : "v"(v[j]));
    asm("v_cvt_f32_ubyte3 %0, %1" : "=v"(f3) : "v"(v[j]));
    S += s[j];
    a0 = fmaf(s[j], f0, a0);
    a1 = fmaf(s[j], f1, a1);
    a2 = fmaf(s[j], f2, a2);
    a3 = fmaf(s[j], f3, a3);
  }
  const float sc = 1.0f / 17.0f, bias = 128.0f * S;
  a0 = (a0 - bias) * sc; a1 = (a1 - bias) * sc;
  a2 = (a2 - bias) * sc; a3 = (a3 - bias) * sc;
  a0 = (a0 >= 0.f) ? a0 : ALPHA * a0;
  a1 = (a1 >= 0.f) ? a1 : ALPHA * a1;
  a2 = (a2 >= 0.f) ? a2 : ALPHA * a2;
  a3 = (a3 >= 0.f) ? a3 : ALPHA * a3;

  float ss = a0 * a0 + a1 * a1 + a2 * a2 + a3 * a3;
  ss += __shfl_xor(ss, 1);  ss += __shfl_xor(ss, 2);
  ss += __shfl_xor(ss, 4);  ss += __shfl_xor(ss, 8);
  ss += __shfl_xor(ss, 16); ss += __shfl_xor(ss, 32);
  const float inv = 1.0f / fmaxf(sqrtf(ss), 1e-12f);

  f32x4 o = {a0 * inv, a1 * inv, a2 * inv, a3 * inv};
  __builtin_nontemporal_store(o, (f32x4*)(out + (size_t)node * 256 + lane * 4));
}

extern "C" void kernel_launch(void* const* d_in, const int* in_sizes, int n_in,
                              void* d_out, int out_size, void* d_ws, size_t ws_size,
                              hipStream_t stream) {
  const float* h = (const float*)d_in[0];
  const int* nbr = (const int*)d_in[1];
  const float* W = (const float*)d_in[2];
  float* out = (float*)d_out;

  u16* Wb = (u16*)d_ws;                                  // 128 KB
  float* scale = (float*)((char*)d_ws + (1 << 17));      // 400 KB f32 row scales
  u8* Yq = (u8*)((char*)d_ws + (1 << 20));               // 25.6 MB int8 Y

  prep_w_kernel<<<32, 256, 0, stream>>>(W, Wb);
  gemm_kernel<<<N_NODES / 32, 256, 0, stream>>>(h, Wb, Yq, scale);
  gather_kernel<<<N_NODES / 4, 256, 0, stream>>>(Yq, scale, nbr, out);
}